// Round 2
// baseline (1148.635 us; speedup 1.0000x reference)
//
#include <hip/hip_runtime.h>
#include <stdint.h>

// Problem dims (fixed)
#define B_  4
#define L_  4096
#define D_  1024
#define H_  16
#define DH  64
#define M_  (B_*L_)   // 16384 rows

typedef _Float16 f16;
typedef __attribute__((ext_vector_type(8))) _Float16 f16x8;
typedef __attribute__((ext_vector_type(4))) _Float16 f16x4;
typedef __attribute__((ext_vector_type(4))) float    f32x4;

// ---------------- async global->LDS (16B per lane) ----------------
__device__ __forceinline__ void cp16(const void* g, void* l) {
  __builtin_amdgcn_global_load_lds(
      (const __attribute__((address_space(1))) void*)g,
      (__attribute__((address_space(3))) void*)l,
      16, 0, 0);
}

// ---------------- fp32 -> fp16 cast (8 elems/thread) ----------------
__global__ __launch_bounds__(256) void k_cvt_f16(const float* __restrict__ x,
                                                 f16* __restrict__ y, int n8) {
  int i = blockIdx.x * 256 + threadIdx.x;
  if (i >= n8) return;
  const float4* xv = (const float4*)x;
  float4 a = xv[2*i], b = xv[2*i+1];
  f16x8 o;
  o[0]=(f16)a.x; o[1]=(f16)a.y; o[2]=(f16)a.z; o[3]=(f16)a.w;
  o[4]=(f16)b.x; o[5]=(f16)b.y; o[6]=(f16)b.z; o[7]=(f16)b.w;
  ((f16x8*)y)[i] = o;
}

// ---------------- fp32 weight -> fp16 hi + fp16 lo residual ----------------
__global__ __launch_bounds__(256) void k_split_w(const float* __restrict__ x,
                                                 f16* __restrict__ hi,
                                                 f16* __restrict__ lo, int n4) {
  int i = blockIdx.x * 256 + threadIdx.x;
  if (i >= n4) return;
  float4 a = ((const float4*)x)[i];
  f16 h0=(f16)a.x, h1=(f16)a.y, h2=(f16)a.z, h3=(f16)a.w;
  f16x4 hv = {h0, h1, h2, h3};
  f16x4 lv = {(f16)(a.x-(float)h0), (f16)(a.y-(float)h1),
              (f16)(a.z-(float)h2), (f16)(a.w-(float)h3)};
  ((f16x4*)hi)[i] = hv;
  ((f16x4*)lo)[i] = lv;
}

// ---------------- GEMM: C = A * (Bhi+Blo)^T + bias ----------------
// A: M x K fp16 row-major; Bhi/Blo: N x K fp16 row-major; C: M x N fp32.
// 128x128 tile, BK=32, 256 threads (4 waves, each 64x64 = 4x4 MFMA 16x16x32).
__global__ __launch_bounds__(256) void k_gemm_wsplit(
    const f16* __restrict__ A, const f16* __restrict__ Bhi,
    const f16* __restrict__ Blo, const float* __restrict__ bias,
    float* __restrict__ C, int M, int N, int K) {
  __shared__ __align__(16) f16 sA [128*32];
  __shared__ __align__(16) f16 sBh[128*32];
  __shared__ __align__(16) f16 sBl[128*32];
  const int t = threadIdx.x;
  const int nbn = N >> 7;
  const int bm = (blockIdx.x / nbn) << 7;
  const int bn = (blockIdx.x % nbn) << 7;
  const int lane = t & 63, wave = t >> 6;
  const int wm = (wave & 1) << 6, wn = (wave >> 1) << 6;
  // staging: chunk c = t and t+256; row = c>>2 (0..127), col-chunk = (c&3)*8
  const int rowA = t >> 2;
  const int cc   = (t & 3) << 3;

  const f16* Ag   = A   + (size_t)(bm + rowA) * K + cc;
  const f16* Ag2  = Ag  + (size_t)64 * K;
  const f16* Bgh  = Bhi + (size_t)(bn + rowA) * K + cc;
  const f16* Bgh2 = Bgh + (size_t)64 * K;
  const f16* Bgl  = Blo + (size_t)(bn + rowA) * K + cc;
  const f16* Bgl2 = Bgl + (size_t)64 * K;

  f16* lA   = &sA [t * 8];  f16* lA2  = &sA [(t + 256) * 8];
  f16* lBh  = &sBh[t * 8];  f16* lBh2 = &sBh[(t + 256) * 8];
  f16* lBl  = &sBl[t * 8];  f16* lBl2 = &sBl[(t + 256) * 8];

  f32x4 acc[4][4] = {};
  const int fm = lane & 15;            // m (or n) within 16-tile
  const int fk = (lane >> 4) << 3;     // k offset: quad*8

  for (int k0 = 0; k0 < K; k0 += 32) {
    __syncthreads();
    cp16(Ag  + k0, lA );  cp16(Ag2  + k0, lA2 );
    cp16(Bgh + k0, lBh);  cp16(Bgh2 + k0, lBh2);
    cp16(Bgl + k0, lBl);  cp16(Bgl2 + k0, lBl2);
    __syncthreads();
    f16x8 af[4], bh[4], bl[4];
#pragma unroll
    for (int i = 0; i < 4; ++i) {
      af[i] = *(const f16x8*)&sA [(wm + i*16 + fm) * 32 + fk];
      bh[i] = *(const f16x8*)&sBh[(wn + i*16 + fm) * 32 + fk];
      bl[i] = *(const f16x8*)&sBl[(wn + i*16 + fm) * 32 + fk];
    }
#pragma unroll
    for (int i = 0; i < 4; ++i)
#pragma unroll
      for (int j = 0; j < 4; ++j) {
        acc[i][j] = __builtin_amdgcn_mfma_f32_16x16x32_f16(af[i], bh[j], acc[i][j], 0, 0, 0);
        acc[i][j] = __builtin_amdgcn_mfma_f32_16x16x32_f16(af[i], bl[j], acc[i][j], 0, 0, 0);
      }
  }
  // epilogue: D layout col = lane&15, row = (lane>>4)*4 + reg  [m89/m91]
  const int cr   = (lane >> 4) << 2;
  const int ccol = lane & 15;
#pragma unroll
  for (int j = 0; j < 4; ++j) {
    int gn = bn + wn + j*16 + ccol;
    float bv = bias[gn];
#pragma unroll
    for (int i = 0; i < 4; ++i) {
      size_t gm = (size_t)(bm + wm + i*16 + cr);
      float* Cp = C + gm * N + gn;
#pragma unroll
      for (int r = 0; r < 4; ++r) Cp[(size_t)r * N] = acc[i][j][r] + bv;
    }
  }
}

// ---------------- sigmoid + L2-norm per (row, head); optional mask fold ----
__global__ __launch_bounds__(256) void k_qknorm(float* __restrict__ p,
                                                const float* __restrict__ mask,
                                                int useMask) {
  int wave = threadIdx.x >> 6, lane = threadIdx.x & 63;
  int unit = blockIdx.x * 4 + wave;     // (row, head)
  int row = unit >> 4, h = unit & 15;
  float* base = p + (size_t)row * D_ + h * DH;
  float v = base[lane];
  float s = 1.0f / (1.0f + __expf(-v));
  float ss = s * s;
#pragma unroll
  for (int off = 32; off > 0; off >>= 1) ss += __shfl_xor(ss, off, 64);
  float scale = 1.0f / fmaxf(sqrtf(ss), 1e-12f);
  float o = s * scale;
  if (useMask) o *= mask[row];
  base[lane] = o;
}

// ---------------- kvb zero-init (harness poisons ws with 0xAA) -------------
__global__ __launch_bounds__(256) void k_kv_zero(float* __restrict__ kvb) {
  kvb[blockIdx.x * 256 + threadIdx.x] = 0.0f;
}

// ---------------- kv: per (head, L-chunk of 512), atomic accumulate --------
// kvb[head][d][c2], c2 = c (V+) / c+64 (V-)
__global__ __launch_bounds__(256) void k_kv_atomic(const float* __restrict__ Kn,
                                                   const float* __restrict__ V,
                                                   float* __restrict__ kvb) {
  int head = blockIdx.x >> 3, chunk = blockIdx.x & 7;
  int b = head >> 4, h = head & 15;
  __shared__ __align__(16) float sK[8][64];
  __shared__ __align__(16) float sV[8][128];
  int t = threadIdx.x;
  int dg = t >> 4, cg = t & 15;         // thread tile: d = dg*4+i, c2 = cg*8+j
  float acc[4][8] = {};
  size_t rb = ((size_t)b * L_ + (size_t)chunk * 512) * D_ + h * DH;
  const float* Kb = Kn + rb;
  const float* Vb = V + rb;
  for (int l0 = 0; l0 < 512; l0 += 8) {
    __syncthreads();
    int r = t >> 6, d = t & 63;
    sK[r][d]     = Kb[(size_t)(l0 + r) * D_ + d];
    sK[r + 4][d] = Kb[(size_t)(l0 + r + 4) * D_ + d];
    float v0 = Vb[(size_t)(l0 + r) * D_ + d];
    float v1 = Vb[(size_t)(l0 + r + 4) * D_ + d];
    sV[r][d] = fmaxf(v0, 0.f);     sV[r][d + 64] = fminf(v0, 0.f);
    sV[r + 4][d] = fmaxf(v1, 0.f); sV[r + 4][d + 64] = fminf(v1, 0.f);
    __syncthreads();
#pragma unroll
    for (int rr = 0; rr < 8; ++rr) {
      float4 kd = *(const float4*)&sK[rr][dg * 4];
      float4 va = *(const float4*)&sV[rr][cg * 8];
      float4 vb = *(const float4*)&sV[rr][cg * 8 + 4];
      float vv[8] = {va.x, va.y, va.z, va.w, vb.x, vb.y, vb.z, vb.w};
      float kk[4] = {kd.x, kd.y, kd.z, kd.w};
#pragma unroll
      for (int i = 0; i < 4; ++i)
#pragma unroll
        for (int j = 0; j < 8; ++j) acc[i][j] += kk[i] * vv[j];
    }
  }
  float* pb = kvb + (size_t)head * 8192;
#pragma unroll
  for (int i = 0; i < 4; ++i)
#pragma unroll
    for (int j = 0; j < 8; ++j)
      atomicAdd(&pb[(dg * 4 + i) * 128 + cg * 8 + j], acc[i][j]);
}

// ---------------- heads: o = l2n(Q@kv+) + l2n(Q@kv-), write fp16 ----------
__global__ __launch_bounds__(256) void k_heads(const float* __restrict__ Qn,
                                               const float* __restrict__ kv,
                                               f16* __restrict__ O) {
  __shared__ __align__(16) float sP[64 * 64];
  __shared__ __align__(16) float sM[64 * 64];
  __shared__ __align__(16) float sQ[4][64];
  int head = blockIdx.x >> 3, chunk = blockIdx.x & 7;
  int b = head >> 4, h = head & 15;
  int t = threadIdx.x, wave = t >> 6, lane = t & 63;
  const float* kvp = kv + (size_t)head * 8192;
  for (int s = t; s < 4096; s += 256) {
    int d = s >> 6, c = s & 63;
    sP[s] = kvp[d * 128 + c];
    sM[s] = kvp[d * 128 + 64 + c];
  }
  __syncthreads();
  size_t rb = (size_t)b * L_ + (size_t)chunk * 512;
  for (int li = wave; li < 512; li += 4) {
    size_t row = rb + li;
    const float* q = Qn + row * D_ + h * DH;
    sQ[wave][lane] = q[lane];
    __syncthreads();   // uniform: 128 iters for every wave
    float hp = 0.f, hm = 0.f;
#pragma unroll
    for (int d0 = 0; d0 < 64; d0 += 4) {
      float4 q4 = *(const float4*)&sQ[wave][d0];
      hp += q4.x * sP[(d0 + 0) * 64 + lane];  hm += q4.x * sM[(d0 + 0) * 64 + lane];
      hp += q4.y * sP[(d0 + 1) * 64 + lane];  hm += q4.y * sM[(d0 + 1) * 64 + lane];
      hp += q4.z * sP[(d0 + 2) * 64 + lane];  hm += q4.z * sM[(d0 + 2) * 64 + lane];
      hp += q4.w * sP[(d0 + 3) * 64 + lane];  hm += q4.w * sM[(d0 + 3) * 64 + lane];
    }
    float pp = hp * hp, mm = hm * hm;
#pragma unroll
    for (int off = 32; off > 0; off >>= 1) {
      pp += __shfl_xor(pp, off, 64);
      mm += __shfl_xor(mm, off, 64);
    }
    float o = hp / fmaxf(sqrtf(pp), 1e-12f) + hm / fmaxf(sqrtf(mm), 1e-12f);
    O[row * D_ + h * DH + lane] = (f16)o;
  }
}

// ---------------- launch ----------------
extern "C" void kernel_launch(void* const* d_in, const int* in_sizes, int n_in,
                              void* d_out, int out_size, void* d_ws, size_t ws_size,
                              hipStream_t stream) {
  const float* queries = (const float*)d_in[0];
  const float* values  = (const float*)d_in[1];
  const float* keys    = (const float*)d_in[2];
  const float* mask    = (const float*)d_in[3];
  const float* Wq = (const float*)d_in[4];  const float* bq = (const float*)d_in[5];
  const float* Wk = (const float*)d_in[6];  const float* bk = (const float*)d_in[7];
  const float* Wv = (const float*)d_in[8];  const float* bv = (const float*)d_in[9];
  const float* Wo = (const float*)d_in[10]; const float* bo = (const float*)d_in[11];
  float* out = (float*)d_out;

  const size_t MB = 1024ull * 1024ull;
  const size_t NEED = 242 * MB;
  if (ws_size < NEED) return;   // diagnostic guard: no launch -> clean absmax fail

  char* ws = (char*)d_ws;
  const size_t DD = (size_t)D_ * D_;        // 1M elems
  f16*   WH   = (f16*)(ws);                 // 4 x 2MB = 8MB
  f16*   WL   = (f16*)(ws + 8 * MB);        // 8MB
  f16*   Ah   = (f16*)(ws + 16 * MB);       // 32MB (reused: q, k, v casts; heads out)
  float* kvb  = (float*)(ws + 48 * MB);     // 2MB
  float* qp   = (float*)(ws + 50 * MB);     // 64MB
  float* kp   = (float*)(ws + 114 * MB);    // 64MB
  float* vp   = (float*)(ws + 178 * MB);    // 64MB  (ends at 242MB)

  const int DD4 = (int)(DD / 4);            // 262144
  k_split_w<<<DD4 / 256, 256, 0, stream>>>(Wq, WH + 0 * DD, WL + 0 * DD, DD4);
  k_split_w<<<DD4 / 256, 256, 0, stream>>>(Wk, WH + 1 * DD, WL + 1 * DD, DD4);
  k_split_w<<<DD4 / 256, 256, 0, stream>>>(Wv, WH + 2 * DD, WL + 2 * DD, DD4);
  k_split_w<<<DD4 / 256, 256, 0, stream>>>(Wo, WH + 3 * DD, WL + 3 * DD, DD4);

  const int n8 = M_ * D_ / 8;               // 2M
  const int gGemm = (M_ / 128) * (D_ / 128);  // 1024 blocks

  k_cvt_f16<<<n8 / 256, 256, 0, stream>>>(queries, Ah, n8);
  k_gemm_wsplit<<<gGemm, 256, 0, stream>>>(Ah, WH + 0 * DD, WL + 0 * DD, bq, qp, M_, D_, D_);
  k_cvt_f16<<<n8 / 256, 256, 0, stream>>>(keys, Ah, n8);
  k_gemm_wsplit<<<gGemm, 256, 0, stream>>>(Ah, WH + 1 * DD, WL + 1 * DD, bk, kp, M_, D_, D_);
  k_cvt_f16<<<n8 / 256, 256, 0, stream>>>(values, Ah, n8);
  k_gemm_wsplit<<<gGemm, 256, 0, stream>>>(Ah, WH + 2 * DD, WL + 2 * DD, bv, vp, M_, D_, D_);

  k_qknorm<<<M_ * H_ / 4, 256, 0, stream>>>(qp, nullptr, 0);
  k_qknorm<<<M_ * H_ / 4, 256, 0, stream>>>(kp, mask, 1);

  k_kv_zero<<<64 * 8192 / 256, 256, 0, stream>>>(kvb);
  k_kv_atomic<<<64 * 8, 256, 0, stream>>>(kp, vp, kvb);
  k_heads<<<64 * 8, 256, 0, stream>>>(qp, kvb, Ah);

  k_gemm_wsplit<<<gGemm, 256, 0, stream>>>(Ah, WH + 3 * DD, WL + 3 * DD, bo, out, M_, D_, D_);
}

// Round 3
// 759.235 us; speedup vs baseline: 1.5129x; 1.5129x over previous
//
#include <hip/hip_runtime.h>
#include <stdint.h>

// Problem dims (fixed)
#define B_  4
#define L_  4096
#define D_  1024
#define H_  16
#define DH  64
#define M_  (B_*L_)   // 16384 rows

typedef _Float16 f16;
typedef __attribute__((ext_vector_type(8))) _Float16 f16x8;
typedef __attribute__((ext_vector_type(4))) _Float16 f16x4;
typedef __attribute__((ext_vector_type(4))) float    f32x4;

// ---------------- async global->LDS (16B per lane) ----------------
__device__ __forceinline__ void cp16(const void* g, void* l) {
  __builtin_amdgcn_global_load_lds(
      (const __attribute__((address_space(1))) void*)g,
      (__attribute__((address_space(3))) void*)l,
      16, 0, 0);
}

// ---------------- fp32 -> fp16 cast (8 elems/thread) ----------------
__global__ __launch_bounds__(256) void k_cvt_f16(const float* __restrict__ x,
                                                 f16* __restrict__ y, int n8) {
  int i = blockIdx.x * 256 + threadIdx.x;
  if (i >= n8) return;
  const float4* xv = (const float4*)x;
  float4 a = xv[2*i], b = xv[2*i+1];
  f16x8 o;
  o[0]=(f16)a.x; o[1]=(f16)a.y; o[2]=(f16)a.z; o[3]=(f16)a.w;
  o[4]=(f16)b.x; o[5]=(f16)b.y; o[6]=(f16)b.z; o[7]=(f16)b.w;
  ((f16x8*)y)[i] = o;
}

// ---------------- fp32 weight -> fp16 hi + fp16 lo residual ----------------
__global__ __launch_bounds__(256) void k_split_w(const float* __restrict__ x,
                                                 f16* __restrict__ hi,
                                                 f16* __restrict__ lo, int n4) {
  int i = blockIdx.x * 256 + threadIdx.x;
  if (i >= n4) return;
  float4 a = ((const float4*)x)[i];
  f16 h0=(f16)a.x, h1=(f16)a.y, h2=(f16)a.z, h3=(f16)a.w;
  f16x4 hv = {h0, h1, h2, h3};
  f16x4 lv = {(f16)(a.x-(float)h0), (f16)(a.y-(float)h1),
              (f16)(a.z-(float)h2), (f16)(a.w-(float)h3)};
  ((f16x4*)hi)[i] = hv;
  ((f16x4*)lo)[i] = lv;
}

// ---------------- GEMM (hi-only) with fused epilogues ----------------
// C = A * Bh^T + bias. mode 0: fp32 C. mode 1: sigmoid+l2norm(64-col head
// group)+mask -> fp32 Cf. mode 2: sigmoid+l2norm -> f16 Ch.
__global__ __launch_bounds__(256) void k_gemm_hi(
    const f16* __restrict__ A, const f16* __restrict__ Bh,
    const float* __restrict__ bias, const float* __restrict__ mask,
    float* __restrict__ Cf, f16* __restrict__ Ch, int mode,
    int M, int N, int K) {
  __shared__ __align__(16) f16 sA[128*32];
  __shared__ __align__(16) f16 sB[128*32];
  const int t = threadIdx.x;
  const int nbn = N >> 7;
  const int bm = (blockIdx.x / nbn) << 7;
  const int bn = (blockIdx.x % nbn) << 7;
  const int lane = t & 63, wave = t >> 6;
  const int wm = (wave & 1) << 6, wn = (wave >> 1) << 6;
  const int rowA = t >> 2;
  const int cc   = (t & 3) << 3;

  const f16* Ag  = A  + (size_t)(bm + rowA) * K + cc;
  const f16* Ag2 = Ag + (size_t)64 * K;
  const f16* Bg  = Bh + (size_t)(bn + rowA) * K + cc;
  const f16* Bg2 = Bg + (size_t)64 * K;
  f16* lA  = &sA[t * 8];  f16* lA2 = &sA[(t + 256) * 8];
  f16* lB  = &sB[t * 8];  f16* lB2 = &sB[(t + 256) * 8];

  f32x4 acc[4][4] = {};
  const int fm = lane & 15;
  const int fk = (lane >> 4) << 3;

  for (int k0 = 0; k0 < K; k0 += 32) {
    __syncthreads();
    cp16(Ag + k0, lA);  cp16(Ag2 + k0, lA2);
    cp16(Bg + k0, lB);  cp16(Bg2 + k0, lB2);
    __syncthreads();
    f16x8 af[4], bf[4];
#pragma unroll
    for (int i = 0; i < 4; ++i) {
      af[i] = *(const f16x8*)&sA[(wm + i*16 + fm) * 32 + fk];
      bf[i] = *(const f16x8*)&sB[(wn + i*16 + fm) * 32 + fk];
    }
#pragma unroll
    for (int i = 0; i < 4; ++i)
#pragma unroll
      for (int j = 0; j < 4; ++j)
        acc[i][j] = __builtin_amdgcn_mfma_f32_16x16x32_f16(af[i], bf[j], acc[i][j], 0, 0, 0);
  }
  // D layout: col = lane&15, row = (lane>>4)*4 + reg  [m89/m91]
  const int cr   = (lane >> 4) << 2;
  const int ccol = lane & 15;
  if (mode == 0) {
#pragma unroll
    for (int j = 0; j < 4; ++j) {
      int gn = bn + wn + j*16 + ccol;
      float bv = bias[gn];
#pragma unroll
      for (int i = 0; i < 4; ++i) {
        float* Cp = Cf + (size_t)(bm + wm + i*16 + cr) * N + gn;
#pragma unroll
        for (int r = 0; r < 4; ++r) Cp[(size_t)r * N] = acc[i][j][r] + bv;
      }
    }
  } else {
    float bvj[4];
#pragma unroll
    for (int j = 0; j < 4; ++j) bvj[j] = bias[bn + wn + j*16 + ccol];
#pragma unroll
    for (int i = 0; i < 4; ++i)
#pragma unroll
      for (int r = 0; r < 4; ++r) {
        int gm = bm + wm + i*16 + cr + r;
        float s[4], ss = 0.f;
#pragma unroll
        for (int j = 0; j < 4; ++j) {
          float v = acc[i][j][r] + bvj[j];
          s[j] = 1.0f / (1.0f + __expf(-v));
          ss += s[j] * s[j];
        }
        ss += __shfl_xor(ss, 1, 64);
        ss += __shfl_xor(ss, 2, 64);
        ss += __shfl_xor(ss, 4, 64);
        ss += __shfl_xor(ss, 8, 64);
        float sc = 1.0f / fmaxf(sqrtf(ss), 1e-12f);
        if (mode == 1) {
          sc *= mask[gm];
#pragma unroll
          for (int j = 0; j < 4; ++j)
            Cf[(size_t)gm * N + bn + wn + j*16 + ccol] = s[j] * sc;
        } else {
#pragma unroll
          for (int j = 0; j < 4; ++j)
            Ch[(size_t)gm * N + bn + wn + j*16 + ccol] = (f16)(s[j] * sc);
        }
      }
  }
}

// ---------------- GEMM (weight-split): C = A*(Bhi+Blo)^T + bias, fp32 ------
__global__ __launch_bounds__(256) void k_gemm_ws(
    const f16* __restrict__ A, const f16* __restrict__ Bhi,
    const f16* __restrict__ Blo, const float* __restrict__ bias,
    float* __restrict__ C, int M, int N, int K) {
  __shared__ __align__(16) f16 sA [128*32];
  __shared__ __align__(16) f16 sBh[128*32];
  __shared__ __align__(16) f16 sBl[128*32];
  const int t = threadIdx.x;
  const int nbn = N >> 7;
  const int bm = (blockIdx.x / nbn) << 7;
  const int bn = (blockIdx.x % nbn) << 7;
  const int lane = t & 63, wave = t >> 6;
  const int wm = (wave & 1) << 6, wn = (wave >> 1) << 6;
  const int rowA = t >> 2;
  const int cc   = (t & 3) << 3;

  const f16* Ag   = A   + (size_t)(bm + rowA) * K + cc;
  const f16* Ag2  = Ag  + (size_t)64 * K;
  const f16* Bgh  = Bhi + (size_t)(bn + rowA) * K + cc;
  const f16* Bgh2 = Bgh + (size_t)64 * K;
  const f16* Bgl  = Blo + (size_t)(bn + rowA) * K + cc;
  const f16* Bgl2 = Bgl + (size_t)64 * K;

  f16* lA   = &sA [t * 8];  f16* lA2  = &sA [(t + 256) * 8];
  f16* lBh  = &sBh[t * 8];  f16* lBh2 = &sBh[(t + 256) * 8];
  f16* lBl  = &sBl[t * 8];  f16* lBl2 = &sBl[(t + 256) * 8];

  f32x4 acc[4][4] = {};
  const int fm = lane & 15;
  const int fk = (lane >> 4) << 3;

  for (int k0 = 0; k0 < K; k0 += 32) {
    __syncthreads();
    cp16(Ag  + k0, lA );  cp16(Ag2  + k0, lA2 );
    cp16(Bgh + k0, lBh);  cp16(Bgh2 + k0, lBh2);
    cp16(Bgl + k0, lBl);  cp16(Bgl2 + k0, lBl2);
    __syncthreads();
    f16x8 af[4], bh[4], bl[4];
#pragma unroll
    for (int i = 0; i < 4; ++i) {
      af[i] = *(const f16x8*)&sA [(wm + i*16 + fm) * 32 + fk];
      bh[i] = *(const f16x8*)&sBh[(wn + i*16 + fm) * 32 + fk];
      bl[i] = *(const f16x8*)&sBl[(wn + i*16 + fm) * 32 + fk];
    }
#pragma unroll
    for (int i = 0; i < 4; ++i)
#pragma unroll
      for (int j = 0; j < 4; ++j) {
        acc[i][j] = __builtin_amdgcn_mfma_f32_16x16x32_f16(af[i], bh[j], acc[i][j], 0, 0, 0);
        acc[i][j] = __builtin_amdgcn_mfma_f32_16x16x32_f16(af[i], bl[j], acc[i][j], 0, 0, 0);
      }
  }
  const int cr   = (lane >> 4) << 2;
  const int ccol = lane & 15;
#pragma unroll
  for (int j = 0; j < 4; ++j) {
    int gn = bn + wn + j*16 + ccol;
    float bv = bias[gn];
#pragma unroll
    for (int i = 0; i < 4; ++i) {
      float* Cp = C + (size_t)(bm + wm + i*16 + cr) * N + gn;
#pragma unroll
      for (int r = 0; r < 4; ++r) Cp[(size_t)r * N] = acc[i][j][r] + bv;
    }
  }
}

// ---------------- kvb zero-init ----------------
__global__ __launch_bounds__(256) void k_kv_zero(float* __restrict__ kvb) {
  kvb[blockIdx.x * 256 + threadIdx.x] = 0.0f;
}

// ---------------- kv: per (head, L-chunk of 512), atomic accumulate --------
// kvb[head][d][c2], c2 = c (V+) / c+64 (V-)
__global__ __launch_bounds__(256) void k_kv_atomic(const float* __restrict__ Kn,
                                                   const float* __restrict__ V,
                                                   float* __restrict__ kvb) {
  int head = blockIdx.x >> 3, chunk = blockIdx.x & 7;
  int b = head >> 4, h = head & 15;
  __shared__ __align__(16) float sK[8][64];
  __shared__ __align__(16) float sV[8][128];
  int t = threadIdx.x;
  int dg = t >> 4, cg = t & 15;
  float acc[4][8] = {};
  size_t rb = ((size_t)b * L_ + (size_t)chunk * 512) * D_ + h * DH;
  const float* Kb = Kn + rb;
  const float* Vb = V + rb;
  for (int l0 = 0; l0 < 512; l0 += 8) {
    __syncthreads();
    int r = t >> 6, d = t & 63;
    sK[r][d]     = Kb[(size_t)(l0 + r) * D_ + d];
    sK[r + 4][d] = Kb[(size_t)(l0 + r + 4) * D_ + d];
    float v0 = Vb[(size_t)(l0 + r) * D_ + d];
    float v1 = Vb[(size_t)(l0 + r + 4) * D_ + d];
    sV[r][d] = fmaxf(v0, 0.f);     sV[r][d + 64] = fminf(v0, 0.f);
    sV[r + 4][d] = fmaxf(v1, 0.f); sV[r + 4][d + 64] = fminf(v1, 0.f);
    __syncthreads();
#pragma unroll
    for (int rr = 0; rr < 8; ++rr) {
      float4 kd = *(const float4*)&sK[rr][dg * 4];
      float4 va = *(const float4*)&sV[rr][cg * 8];
      float4 vb = *(const float4*)&sV[rr][cg * 8 + 4];
      float vv[8] = {va.x, va.y, va.z, va.w, vb.x, vb.y, vb.z, vb.w};
      float kk[4] = {kd.x, kd.y, kd.z, kd.w};
#pragma unroll
      for (int i = 0; i < 4; ++i)
#pragma unroll
        for (int j = 0; j < 8; ++j) acc[i][j] += kk[i] * vv[j];
    }
  }
  float* pb = kvb + (size_t)head * 8192;
#pragma unroll
  for (int i = 0; i < 4; ++i)
#pragma unroll
    for (int j = 0; j < 8; ++j)
      atomicAdd(&pb[(dg * 4 + i) * 128 + cg * 8 + j], acc[i][j]);
}

// ---------------- kv fp32 [head][d][c] -> f16 transposed [head][c][d] ------
__global__ __launch_bounds__(256) void k_kv_cvt(const float* __restrict__ kvb,
                                                f16* __restrict__ kvh) {
  int head = blockIdx.x, t = threadIdx.x;
  int c = t >> 1, half = t & 1;
  const float* src = kvb + (size_t)head * 8192 + half * 32 * 128 + c;
  f16* dst = kvh + (size_t)head * 8192 + c * 64 + half * 32;
  f16 buf[32];
#pragma unroll
  for (int kk = 0; kk < 32; ++kk) buf[kk] = (f16)src[kk * 128];
#pragma unroll
  for (int q = 0; q < 4; ++q) ((f16x8*)dst)[q] = *(const f16x8*)&buf[q * 8];
}

// ---------------- heads via MFMA: o = l2n(Q@kv+) + l2n(Q@kv-), f16 out -----
// per block: head, 128-row tile. C(128x128) = Q(128x64) @ kv^T(128x64)^T.
__global__ __launch_bounds__(256) void k_heads_mfma(const f16* __restrict__ Qh,
                                                    const f16* __restrict__ kvh,
                                                    f16* __restrict__ O) {
  __shared__ __align__(16) f16 sQ [128 * 64];
  __shared__ __align__(16) f16 sKV[128 * 64];
  int bi = blockIdx.x;
  int head = bi >> 5, mt = bi & 31;
  int b = head >> 4, h = head & 15;
  int t = threadIdx.x, lane = t & 63, wave = t >> 6;
  size_t qbase = ((size_t)(b * L_ + mt * 128)) * D_ + h * DH;
#pragma unroll
  for (int p = 0; p < 4; ++p) {
    int row = p * 32 + (t >> 3);
    cp16(Qh + qbase + (size_t)row * D_ + (t & 7) * 8, &sQ[p * 2048 + t * 8]);
  }
  const f16* kvp = kvh + (size_t)head * 8192;
#pragma unroll
  for (int p = 0; p < 4; ++p)
    cp16(kvp + p * 2048 + t * 8, &sKV[p * 2048 + t * 8]);
  __syncthreads();

  const int fm = lane & 15, fk = (lane >> 4) << 3;
  const int wm = wave * 32;
  f32x4 acc[2][8] = {};
#pragma unroll
  for (int ks = 0; ks < 2; ++ks) {
    f16x8 a0 = *(const f16x8*)&sQ[(wm + fm) * 64 + ks * 32 + fk];
    f16x8 a1 = *(const f16x8*)&sQ[(wm + 16 + fm) * 64 + ks * 32 + fk];
#pragma unroll
    for (int j = 0; j < 8; ++j) {
      f16x8 bj = *(const f16x8*)&sKV[(j * 16 + fm) * 64 + ks * 32 + fk];
      acc[0][j] = __builtin_amdgcn_mfma_f32_16x16x32_f16(a0, bj, acc[0][j], 0, 0, 0);
      acc[1][j] = __builtin_amdgcn_mfma_f32_16x16x32_f16(a1, bj, acc[1][j], 0, 0, 0);
    }
  }
  // epilogue: split-norm P (j 0-3) and M (j 4-7), combine, write f16
  const int cr = (lane >> 4) << 2, ccol = lane & 15;
  size_t obase = qbase;
#pragma unroll
  for (int i = 0; i < 2; ++i)
#pragma unroll
    for (int r = 0; r < 4; ++r) {
      int row = wm + i * 16 + cr + r;
      float sp = 0.f, sm = 0.f;
#pragma unroll
      for (int j = 0; j < 4; ++j) {
        sp += acc[i][j][r] * acc[i][j][r];
        sm += acc[i][j + 4][r] * acc[i][j + 4][r];
      }
      sp += __shfl_xor(sp, 1, 64); sm += __shfl_xor(sm, 1, 64);
      sp += __shfl_xor(sp, 2, 64); sm += __shfl_xor(sm, 2, 64);
      sp += __shfl_xor(sp, 4, 64); sm += __shfl_xor(sm, 4, 64);
      sp += __shfl_xor(sp, 8, 64); sm += __shfl_xor(sm, 8, 64);
      float rp = 1.0f / fmaxf(sqrtf(sp), 1e-12f);
      float rm = 1.0f / fmaxf(sqrtf(sm), 1e-12f);
#pragma unroll
      for (int j = 0; j < 4; ++j) {
        float o = acc[i][j][r] * rp + acc[i][j + 4][r] * rm;
        O[obase + (size_t)row * D_ + j * 16 + ccol] = (f16)o;
      }
    }
}

// ---------------- launch ----------------
extern "C" void kernel_launch(void* const* d_in, const int* in_sizes, int n_in,
                              void* d_out, int out_size, void* d_ws, size_t ws_size,
                              hipStream_t stream) {
  const float* queries = (const float*)d_in[0];
  const float* values  = (const float*)d_in[1];
  const float* keys    = (const float*)d_in[2];
  const float* mask    = (const float*)d_in[3];
  const float* Wq = (const float*)d_in[4];  const float* bq = (const float*)d_in[5];
  const float* Wk = (const float*)d_in[6];  const float* bk = (const float*)d_in[7];
  const float* Wv = (const float*)d_in[8];  const float* bv = (const float*)d_in[9];
  const float* Wo = (const float*)d_in[10]; const float* bo = (const float*)d_in[11];
  float* out = (float*)d_out;

  const size_t MB = 1024ull * 1024ull;
  const size_t NEED = 208 * MB;
  if (ws_size < NEED) return;   // diagnostic guard (R1 lesson: ws overflow = abort)

  char* ws = (char*)d_ws;
  const size_t DD = (size_t)D_ * D_;        // 1M elems
  f16*   WH  = (f16*)(ws);                  // 4 x 2MB = 8MB (q,k,v,o hi)
  f16*   WL  = (f16*)(ws + 8 * MB);         // 2 x 2MB = 4MB (v,o lo)
  f16*   Ah  = (f16*)(ws + 12 * MB);        // 32MB (A-side f16; reused)
  f16*   Qh  = (f16*)(ws + 44 * MB);        // 32MB (normalized Q, f16)
  float* kvb = (float*)(ws + 76 * MB);      // 2MB
  f16*   kvh = (f16*)(ws + 78 * MB);        // 1MB (+1MB pad)
  float* kp  = (float*)(ws + 80 * MB);      // 64MB
  float* vp  = (float*)(ws + 144 * MB);     // 64MB (ends 208MB)

  const int DD8 = (int)(DD / 8);            // 131072
  const int DD4 = (int)(DD / 4);            // 262144
  k_cvt_f16<<<DD8 / 256, 256, 0, stream>>>(Wq, WH + 0 * DD, DD8);
  k_cvt_f16<<<DD8 / 256, 256, 0, stream>>>(Wk, WH + 1 * DD, DD8);
  k_split_w<<<DD4 / 256, 256, 0, stream>>>(Wv, WH + 2 * DD, WL + 0 * DD, DD4);
  k_split_w<<<DD4 / 256, 256, 0, stream>>>(Wo, WH + 3 * DD, WL + 1 * DD, DD4);

  const int n8 = M_ * D_ / 8;               // 2M
  const int gGemm = (M_ / 128) * (D_ / 128);  // 1024 blocks

  k_cvt_f16<<<n8 / 256, 256, 0, stream>>>(queries, Ah, n8);
  k_gemm_hi<<<gGemm, 256, 0, stream>>>(Ah, WH + 0 * DD, bq, nullptr, nullptr, Qh, 2, M_, D_, D_);
  k_cvt_f16<<<n8 / 256, 256, 0, stream>>>(keys, Ah, n8);
  k_gemm_hi<<<gGemm, 256, 0, stream>>>(Ah, WH + 1 * DD, bk, mask, kp, nullptr, 1, M_, D_, D_);
  k_cvt_f16<<<n8 / 256, 256, 0, stream>>>(values, Ah, n8);
  k_gemm_ws<<<gGemm, 256, 0, stream>>>(Ah, WH + 2 * DD, WL + 0 * DD, bv, vp, M_, D_, D_);

  k_kv_zero<<<64 * 8192 / 256, 256, 0, stream>>>(kvb);
  k_kv_atomic<<<64 * 8, 256, 0, stream>>>(kp, vp, kvb);
  k_kv_cvt<<<64, 256, 0, stream>>>(kvb, kvh);
  k_heads_mfma<<<64 * 32, 256, 0, stream>>>(Qh, kvh, Ah);

  k_gemm_ws<<<gGemm, 256, 0, stream>>>(Ah, WH + 3 * DD, WL + 1 * DD, bo, out, M_, D_, D_);
}

// Round 4
// 627.466 us; speedup vs baseline: 1.8306x; 1.2100x over previous
//
#include <hip/hip_runtime.h>
#include <stdint.h>

// Problem dims (fixed)
#define B_  4
#define L_  4096
#define D_  1024
#define H_  16
#define DH  64
#define M_  (B_*L_)   // 16384 rows

typedef _Float16 f16;
typedef __attribute__((ext_vector_type(8))) _Float16 f16x8;
typedef __attribute__((ext_vector_type(4))) _Float16 f16x4;
typedef __attribute__((ext_vector_type(4))) float    f32x4;

// ---------------- async global->LDS (16B per lane) ----------------
__device__ __forceinline__ void cp16(const void* g, void* l) {
  __builtin_amdgcn_global_load_lds(
      (const __attribute__((address_space(1))) void*)g,
      (__attribute__((address_space(3))) void*)l,
      16, 0, 0);
}

// ---------------- fp32 -> fp16 cast (8 elems/thread) ----------------
__global__ __launch_bounds__(256) void k_cvt_f16(const float* __restrict__ x,
                                                 f16* __restrict__ y, int n8) {
  int i = blockIdx.x * 256 + threadIdx.x;
  if (i >= n8) return;
  const float4* xv = (const float4*)x;
  float4 a = xv[2*i], b = xv[2*i+1];
  f16x8 o;
  o[0]=(f16)a.x; o[1]=(f16)a.y; o[2]=(f16)a.z; o[3]=(f16)a.w;
  o[4]=(f16)b.x; o[5]=(f16)b.y; o[6]=(f16)b.z; o[7]=(f16)b.w;
  ((f16x8*)y)[i] = o;
}

// ---------------- fp32 weight -> fp16 hi + fp16 lo residual ----------------
__global__ __launch_bounds__(256) void k_split_w(const float* __restrict__ x,
                                                 f16* __restrict__ hi,
                                                 f16* __restrict__ lo, int n4) {
  int i = blockIdx.x * 256 + threadIdx.x;
  if (i >= n4) return;
  float4 a = ((const float4*)x)[i];
  f16 h0=(f16)a.x, h1=(f16)a.y, h2=(f16)a.z, h3=(f16)a.w;
  f16x4 hv = {h0, h1, h2, h3};
  f16x4 lv = {(f16)(a.x-(float)h0), (f16)(a.y-(float)h1),
              (f16)(a.z-(float)h2), (f16)(a.w-(float)h3)};
  ((f16x4*)hi)[i] = hv;
  ((f16x4*)lo)[i] = lv;
}

// ---------------- GEMM (hi-only) with fused epilogues ----------------
// C = A * Bh^T + bias. mode 0: fp32 Cf raw.
// mode 1: sigmoid + l2norm over 64-col head group (+ optional mask) -> f16 Ch.
__global__ __launch_bounds__(256) void k_gemm_hi(
    const f16* __restrict__ A, const f16* __restrict__ Bh,
    const float* __restrict__ bias, const float* __restrict__ mask,
    float* __restrict__ Cf, f16* __restrict__ Ch, int mode,
    int M, int N, int K) {
  __shared__ __align__(16) f16 sA[128*32];
  __shared__ __align__(16) f16 sB[128*32];
  const int t = threadIdx.x;
  const int nbn = N >> 7;
  const int bm = (blockIdx.x / nbn) << 7;
  const int bn = (blockIdx.x % nbn) << 7;
  const int lane = t & 63, wave = t >> 6;
  const int wm = (wave & 1) << 6, wn = (wave >> 1) << 6;
  const int rowA = t >> 2;
  const int cc   = (t & 3) << 3;

  const f16* Ag  = A  + (size_t)(bm + rowA) * K + cc;
  const f16* Ag2 = Ag + (size_t)64 * K;
  const f16* Bg  = Bh + (size_t)(bn + rowA) * K + cc;
  const f16* Bg2 = Bg + (size_t)64 * K;
  f16* lA  = &sA[t * 8];  f16* lA2 = &sA[(t + 256) * 8];
  f16* lB  = &sB[t * 8];  f16* lB2 = &sB[(t + 256) * 8];

  f32x4 acc[4][4] = {};
  const int fm = lane & 15;
  const int fk = (lane >> 4) << 3;

  for (int k0 = 0; k0 < K; k0 += 32) {
    __syncthreads();
    cp16(Ag + k0, lA);  cp16(Ag2 + k0, lA2);
    cp16(Bg + k0, lB);  cp16(Bg2 + k0, lB2);
    __syncthreads();
    f16x8 af[4], bf[4];
#pragma unroll
    for (int i = 0; i < 4; ++i) {
      af[i] = *(const f16x8*)&sA[(wm + i*16 + fm) * 32 + fk];
      bf[i] = *(const f16x8*)&sB[(wn + i*16 + fm) * 32 + fk];
    }
#pragma unroll
    for (int i = 0; i < 4; ++i)
#pragma unroll
      for (int j = 0; j < 4; ++j)
        acc[i][j] = __builtin_amdgcn_mfma_f32_16x16x32_f16(af[i], bf[j], acc[i][j], 0, 0, 0);
  }
  // D layout: col = lane&15, row = (lane>>4)*4 + reg  [m89/m91]
  const int cr   = (lane >> 4) << 2;
  const int ccol = lane & 15;
  if (mode == 0) {
#pragma unroll
    for (int j = 0; j < 4; ++j) {
      int gn = bn + wn + j*16 + ccol;
      float bv = bias[gn];
#pragma unroll
      for (int i = 0; i < 4; ++i) {
        float* Cp = Cf + (size_t)(bm + wm + i*16 + cr) * N + gn;
#pragma unroll
        for (int r = 0; r < 4; ++r) Cp[(size_t)r * N] = acc[i][j][r] + bv;
      }
    }
  } else {
    float bvj[4];
#pragma unroll
    for (int j = 0; j < 4; ++j) bvj[j] = bias[bn + wn + j*16 + ccol];
#pragma unroll
    for (int i = 0; i < 4; ++i)
#pragma unroll
      for (int r = 0; r < 4; ++r) {
        int gm = bm + wm + i*16 + cr + r;
        float s[4], ss = 0.f;
#pragma unroll
        for (int j = 0; j < 4; ++j) {
          float v = acc[i][j][r] + bvj[j];
          s[j] = 1.0f / (1.0f + __expf(-v));
          ss += s[j] * s[j];
        }
        ss += __shfl_xor(ss, 1, 64);
        ss += __shfl_xor(ss, 2, 64);
        ss += __shfl_xor(ss, 4, 64);
        ss += __shfl_xor(ss, 8, 64);
        float sc = 1.0f / fmaxf(sqrtf(ss), 1e-12f);
        if (mask) sc *= mask[gm];
#pragma unroll
        for (int j = 0; j < 4; ++j)
          Ch[(size_t)gm * N + bn + wn + j*16 + ccol] = (f16)(s[j] * sc);
      }
  }
}

// ---------------- GEMM (weight-split): C = A*(Bhi+Blo)^T + bias ------------
// Ch != nullptr -> f16 out, else fp32 Cf.
__global__ __launch_bounds__(256) void k_gemm_ws(
    const f16* __restrict__ A, const f16* __restrict__ Bhi,
    const f16* __restrict__ Blo, const float* __restrict__ bias,
    float* __restrict__ Cf, f16* __restrict__ Ch, int M, int N, int K) {
  __shared__ __align__(16) f16 sA [128*32];
  __shared__ __align__(16) f16 sBh[128*32];
  __shared__ __align__(16) f16 sBl[128*32];
  const int t = threadIdx.x;
  const int nbn = N >> 7;
  const int bm = (blockIdx.x / nbn) << 7;
  const int bn = (blockIdx.x % nbn) << 7;
  const int lane = t & 63, wave = t >> 6;
  const int wm = (wave & 1) << 6, wn = (wave >> 1) << 6;
  const int rowA = t >> 2;
  const int cc   = (t & 3) << 3;

  const f16* Ag   = A   + (size_t)(bm + rowA) * K + cc;
  const f16* Ag2  = Ag  + (size_t)64 * K;
  const f16* Bgh  = Bhi + (size_t)(bn + rowA) * K + cc;
  const f16* Bgh2 = Bgh + (size_t)64 * K;
  const f16* Bgl  = Blo + (size_t)(bn + rowA) * K + cc;
  const f16* Bgl2 = Bgl + (size_t)64 * K;

  f16* lA   = &sA [t * 8];  f16* lA2  = &sA [(t + 256) * 8];
  f16* lBh  = &sBh[t * 8];  f16* lBh2 = &sBh[(t + 256) * 8];
  f16* lBl  = &sBl[t * 8];  f16* lBl2 = &sBl[(t + 256) * 8];

  f32x4 acc[4][4] = {};
  const int fm = lane & 15;
  const int fk = (lane >> 4) << 3;

  for (int k0 = 0; k0 < K; k0 += 32) {
    __syncthreads();
    cp16(Ag  + k0, lA );  cp16(Ag2  + k0, lA2 );
    cp16(Bgh + k0, lBh);  cp16(Bgh2 + k0, lBh2);
    cp16(Bgl + k0, lBl);  cp16(Bgl2 + k0, lBl2);
    __syncthreads();
    f16x8 af[4], bh[4], bl[4];
#pragma unroll
    for (int i = 0; i < 4; ++i) {
      af[i] = *(const f16x8*)&sA [(wm + i*16 + fm) * 32 + fk];
      bh[i] = *(const f16x8*)&sBh[(wn + i*16 + fm) * 32 + fk];
      bl[i] = *(const f16x8*)&sBl[(wn + i*16 + fm) * 32 + fk];
    }
#pragma unroll
    for (int i = 0; i < 4; ++i)
#pragma unroll
      for (int j = 0; j < 4; ++j) {
        acc[i][j] = __builtin_amdgcn_mfma_f32_16x16x32_f16(af[i], bh[j], acc[i][j], 0, 0, 0);
        acc[i][j] = __builtin_amdgcn_mfma_f32_16x16x32_f16(af[i], bl[j], acc[i][j], 0, 0, 0);
      }
  }
  const int cr   = (lane >> 4) << 2;
  const int ccol = lane & 15;
#pragma unroll
  for (int j = 0; j < 4; ++j) {
    int gn = bn + wn + j*16 + ccol;
    float bv = bias[gn];
#pragma unroll
    for (int i = 0; i < 4; ++i) {
      size_t gm = (size_t)(bm + wm + i*16 + cr);
      if (Ch) {
#pragma unroll
        for (int r = 0; r < 4; ++r)
          Ch[(gm + r) * N + gn] = (f16)(acc[i][j][r] + bv);
      } else {
        float* Cp = Cf + gm * N + gn;
#pragma unroll
        for (int r = 0; r < 4; ++r) Cp[(size_t)r * N] = acc[i][j][r] + bv;
      }
    }
  }
}

// ---------------- kv via MFMA: per (head, chunk of 512 rows) ---------------
// part[(head*8+chunk)][d][c2] = sum_l K[l][d] * Vsplit[l][c2]
// LDS tiles staged TRANSPOSED (k=l contiguous), stride 72 f16 (conflict-free).
#define SKT 72
__global__ __launch_bounds__(256) void k_kv_mfma(const f16* __restrict__ Kh,
                                                 const f16* __restrict__ Vh,
                                                 float* __restrict__ part) {
  __shared__ __align__(16) f16 sKt[64 * SKT];    // [d][l]
  __shared__ __align__(16) f16 sVt[128 * SKT];   // [c2][l]
  int head = blockIdx.x >> 3, chunk = blockIdx.x & 7;
  int b = head >> 4, h = head & 15;
  int t = threadIdx.x, lane = t & 63, wave = t >> 6;
  int lp = t & 31, g8 = (t >> 5) << 3;
  size_t rowbase = (size_t)b * L_ + (size_t)chunk * 512;
  const f16* Kb = Kh + rowbase * D_ + h * DH;
  const f16* Vb = Vh + rowbase * D_ + h * DH;

  const int fm = lane & 15, fk = (lane >> 4) << 3;
  const int wm2 = (wave & 1) * 2;   // m-tile base (d), 2 of 4
  const int wn4 = (wave >> 1) * 4;  // n-tile base (c2), 4 of 8
  f32x4 acc[2][4] = {};

  for (int l0 = 0; l0 < 512; l0 += 64) {
    __syncthreads();
    {
      const f16* r0 = Kb + (size_t)(l0 + 2*lp) * D_ + g8;
      f16x8 a0 = *(const f16x8*)r0;
      f16x8 a1 = *(const f16x8*)(r0 + D_);
#pragma unroll
      for (int j = 0; j < 8; ++j) {
        union { f16 h2[2]; uint32_t u; } pk;
        pk.h2[0] = a0[j]; pk.h2[1] = a1[j];
        *(uint32_t*)&sKt[(g8 + j) * SKT + 2*lp] = pk.u;
      }
      const f16* v0p = Vb + (size_t)(l0 + 2*lp) * D_ + g8;
      f16x8 b0 = *(const f16x8*)v0p;
      f16x8 b1 = *(const f16x8*)(v0p + D_);
#pragma unroll
      for (int j = 0; j < 8; ++j) {
        float x0 = (float)b0[j], x1 = (float)b1[j];
        union { f16 h2[2]; uint32_t u; } pp, pm;
        pp.h2[0] = (f16)fmaxf(x0, 0.f); pp.h2[1] = (f16)fmaxf(x1, 0.f);
        pm.h2[0] = (f16)fminf(x0, 0.f); pm.h2[1] = (f16)fminf(x1, 0.f);
        *(uint32_t*)&sVt[(g8 + j) * SKT + 2*lp]        = pp.u;
        *(uint32_t*)&sVt[(64 + g8 + j) * SKT + 2*lp]   = pm.u;
      }
    }
    __syncthreads();
#pragma unroll
    for (int ks = 0; ks < 2; ++ks) {
      f16x8 af[2], bf[4];
#pragma unroll
      for (int i = 0; i < 2; ++i)
        af[i] = *(const f16x8*)&sKt[((wm2+i)*16 + fm) * SKT + ks*32 + fk];
#pragma unroll
      for (int j = 0; j < 4; ++j)
        bf[j] = *(const f16x8*)&sVt[((wn4+j)*16 + fm) * SKT + ks*32 + fk];
#pragma unroll
      for (int i = 0; i < 2; ++i)
#pragma unroll
        for (int j = 0; j < 4; ++j)
          acc[i][j] = __builtin_amdgcn_mfma_f32_16x16x32_f16(af[i], bf[j], acc[i][j], 0, 0, 0);
    }
  }
  const int cr = (lane >> 4) << 2, ccol = lane & 15;
  float* pb = part + (size_t)(head * 8 + chunk) * 8192;
#pragma unroll
  for (int i = 0; i < 2; ++i)
#pragma unroll
    for (int j = 0; j < 4; ++j) {
      int d = (wm2 + i) * 16 + cr;
      int c2 = (wn4 + j) * 16 + ccol;
#pragma unroll
      for (int r = 0; r < 4; ++r)
        pb[(d + r) * 128 + c2] = acc[i][j][r];
    }
}

__global__ __launch_bounds__(256) void k_kv_reduce(const float* __restrict__ part,
                                                   float* __restrict__ kv) {
  int i = blockIdx.x * 256 + threadIdx.x;   // over 64*8192
  int head = i >> 13, dc = i & 8191;
  float s = 0.f;
#pragma unroll
  for (int c = 0; c < 8; ++c) s += part[(size_t)(head * 8 + c) * 8192 + dc];
  kv[i] = s;
}

// ---------------- kv fp32 [head][d][c2] -> f16 transposed [head][c2][d] ----
__global__ __launch_bounds__(256) void k_kv_cvt(const float* __restrict__ kvb,
                                                f16* __restrict__ kvh) {
  int head = blockIdx.x, t = threadIdx.x;
  int c = t >> 1, half = t & 1;
  const float* src = kvb + (size_t)head * 8192 + half * 32 * 128 + c;
  f16* dst = kvh + (size_t)head * 8192 + c * 64 + half * 32;
  f16 buf[32];
#pragma unroll
  for (int kk = 0; kk < 32; ++kk) buf[kk] = (f16)src[kk * 128];
#pragma unroll
  for (int q = 0; q < 4; ++q) ((f16x8*)dst)[q] = *(const f16x8*)&buf[q * 8];
}

// ---------------- heads via MFMA: o = l2n(Q@kv+) + l2n(Q@kv-), f16 out -----
// per block: head, 128-row tile. Padded-stride LDS (72 f16) for conflict-free
// fragment reads; manual staging (cp16 can't hit padded rows).
#define SH 72
__global__ __launch_bounds__(256) void k_heads_mfma(const f16* __restrict__ Qh,
                                                    const f16* __restrict__ kvh,
                                                    f16* __restrict__ O) {
  __shared__ __align__(16) f16 sQ [128 * SH];
  __shared__ __align__(16) f16 sKV[128 * SH];
  int bi = blockIdx.x;
  int head = bi >> 5, mt = bi & 31;
  int b = head >> 4, h = head & 15;
  int t = threadIdx.x, lane = t & 63, wave = t >> 6;
  size_t qbase = ((size_t)(b * L_ + mt * 128)) * D_ + h * DH;
  const f16* kvp = kvh + (size_t)head * 8192;
#pragma unroll
  for (int p = 0; p < 4; ++p) {
    int c = p * 256 + t;            // 1024 chunks of 16B
    int row = c >> 3, off = (c & 7) * 8;
    f16x8 q = *(const f16x8*)(Qh + qbase + (size_t)row * D_ + off);
    *(f16x8*)&sQ[row * SH + off] = q;
    f16x8 kv8 = *(const f16x8*)(kvp + row * 64 + off);
    *(f16x8*)&sKV[row * SH + off] = kv8;
  }
  __syncthreads();

  const int fm = lane & 15, fk = (lane >> 4) << 3;
  const int wm = wave * 32;
  f32x4 acc[2][8] = {};
#pragma unroll
  for (int ks = 0; ks < 2; ++ks) {
    f16x8 a0 = *(const f16x8*)&sQ[(wm + fm) * SH + ks * 32 + fk];
    f16x8 a1 = *(const f16x8*)&sQ[(wm + 16 + fm) * SH + ks * 32 + fk];
#pragma unroll
    for (int j = 0; j < 8; ++j) {
      f16x8 bj = *(const f16x8*)&sKV[(j * 16 + fm) * SH + ks * 32 + fk];
      acc[0][j] = __builtin_amdgcn_mfma_f32_16x16x32_f16(a0, bj, acc[0][j], 0, 0, 0);
      acc[1][j] = __builtin_amdgcn_mfma_f32_16x16x32_f16(a1, bj, acc[1][j], 0, 0, 0);
    }
  }
  const int cr = (lane >> 4) << 2, ccol = lane & 15;
#pragma unroll
  for (int i = 0; i < 2; ++i)
#pragma unroll
    for (int r = 0; r < 4; ++r) {
      int row = wm + i * 16 + cr + r;
      float sp = 0.f, sm = 0.f;
#pragma unroll
      for (int j = 0; j < 4; ++j) {
        sp += acc[i][j][r] * acc[i][j][r];
        sm += acc[i][j + 4][r] * acc[i][j + 4][r];
      }
      sp += __shfl_xor(sp, 1, 64); sm += __shfl_xor(sm, 1, 64);
      sp += __shfl_xor(sp, 2, 64); sm += __shfl_xor(sm, 2, 64);
      sp += __shfl_xor(sp, 4, 64); sm += __shfl_xor(sm, 4, 64);
      sp += __shfl_xor(sp, 8, 64); sm += __shfl_xor(sm, 8, 64);
      float rp = 1.0f / fmaxf(sqrtf(sp), 1e-12f);
      float rm = 1.0f / fmaxf(sqrtf(sm), 1e-12f);
#pragma unroll
      for (int j = 0; j < 4; ++j) {
        float o = acc[i][j][r] * rp + acc[i][j + 4][r] * rm;
        O[qbase + (size_t)row * D_ + j * 16 + ccol] = (f16)o;
      }
    }
}

// ---------------- launch ----------------
extern "C" void kernel_launch(void* const* d_in, const int* in_sizes, int n_in,
                              void* d_out, int out_size, void* d_ws, size_t ws_size,
                              hipStream_t stream) {
  const float* queries = (const float*)d_in[0];
  const float* values  = (const float*)d_in[1];
  const float* keys    = (const float*)d_in[2];
  const float* mask    = (const float*)d_in[3];
  const float* Wq = (const float*)d_in[4];  const float* bq = (const float*)d_in[5];
  const float* Wk = (const float*)d_in[6];  const float* bk = (const float*)d_in[7];
  const float* Wv = (const float*)d_in[8];  const float* bv = (const float*)d_in[9];
  const float* Wo = (const float*)d_in[10]; const float* bo = (const float*)d_in[11];
  float* out = (float*)d_out;

  const size_t MB = 1024ull * 1024ull;
  const size_t NEED = 160 * MB;
  if (ws_size < NEED) return;   // guard (R1 lesson: ws overflow = abort)

  char* ws = (char*)d_ws;
  const size_t DD = (size_t)D_ * D_;        // 1M elems
  f16*   WH   = (f16*)(ws);                 // 8MB  (q,k,v,o hi)
  f16*   WL   = (f16*)(ws + 8 * MB);        // 4MB  (v,o lo)
  f16*   Ah   = (f16*)(ws + 12 * MB);       // 32MB (A-side f16; reused as heads out)
  f16*   Qh   = (f16*)(ws + 44 * MB);       // 32MB (normalized Q, f16)
  float* kvb  = (float*)(ws + 76 * MB);     // 2MB
  f16*   kvh  = (f16*)(ws + 78 * MB);       // 1MB (+1MB pad)
  float* part = (float*)(ws + 80 * MB);     // 16MB
  f16*   kp   = (f16*)(ws + 96 * MB);       // 32MB (normalized+masked K, f16)
  f16*   vp   = (f16*)(ws + 128 * MB);      // 32MB (V projection, f16) -> 160MB

  const int DD8 = (int)(DD / 8);            // 131072
  const int DD4 = (int)(DD / 4);            // 262144
  k_cvt_f16<<<DD8 / 256, 256, 0, stream>>>(Wq, WH + 0 * DD, DD8);
  k_cvt_f16<<<DD8 / 256, 256, 0, stream>>>(Wk, WH + 1 * DD, DD8);
  k_split_w<<<DD4 / 256, 256, 0, stream>>>(Wv, WH + 2 * DD, WL + 0 * DD, DD4);
  k_split_w<<<DD4 / 256, 256, 0, stream>>>(Wo, WH + 3 * DD, WL + 1 * DD, DD4);

  const int n8 = M_ * D_ / 8;               // 2M
  const int gGemm = (M_ / 128) * (D_ / 128);  // 1024 blocks

  k_cvt_f16<<<n8 / 256, 256, 0, stream>>>(queries, Ah, n8);
  k_gemm_hi<<<gGemm, 256, 0, stream>>>(Ah, WH + 0 * DD, bq, nullptr, nullptr, Qh, 1, M_, D_, D_);
  k_cvt_f16<<<n8 / 256, 256, 0, stream>>>(keys, Ah, n8);
  k_gemm_hi<<<gGemm, 256, 0, stream>>>(Ah, WH + 1 * DD, bk, mask, nullptr, kp, 1, M_, D_, D_);
  k_cvt_f16<<<n8 / 256, 256, 0, stream>>>(values, Ah, n8);
  k_gemm_ws<<<gGemm, 256, 0, stream>>>(Ah, WH + 2 * DD, WL + 0 * DD, bv, nullptr, vp, M_, D_, D_);

  k_kv_mfma<<<64 * 8, 256, 0, stream>>>(kp, vp, part);
  k_kv_reduce<<<64 * 8192 / 256, 256, 0, stream>>>(part, kvb);
  k_kv_cvt<<<64, 256, 0, stream>>>(kvb, kvh);
  k_heads_mfma<<<64 * 32, 256, 0, stream>>>(Qh, kvh, Ah);

  k_gemm_ws<<<gGemm, 256, 0, stream>>>(Ah, WH + 3 * DD, WL + 1 * DD, bo, out, nullptr, M_, D_, D_);
}